// Round 14
// baseline (316.165 us; speedup 1.0000x reference)
//
#include <hip/hip_runtime.h>
#include <hip/hip_bf16.h>

typedef __bf16 bf16;
typedef __attribute__((ext_vector_type(4))) __bf16 bf16x4;
typedef __attribute__((ext_vector_type(8))) __bf16 bf16x8;
typedef __attribute__((ext_vector_type(4))) float f32x4;

#define MFMA16(a,b,c) __builtin_amdgcn_mfma_f32_16x16x32_bf16((a),(b),(c),0,0,0)

constexpr int BSZ = 4, SEQ = 2048, DIM = 1024, NH = 16, HD = 64;
constexpr long SZ    = (long)BSZ * SEQ * DIM;   // 8M elements (full activation)
constexpr long BSLOT = (long)SEQ * DIM;         // 2M elements (one batch slot)
constexpr long WSZ   = (long)DIM * DIM;         // 1M elements (one weight matrix, 2^20)

// ---- staging loaders: 8 contiguous elements -> bf16x8 ----------------------
__device__ inline bf16x8 ld8(const bf16* p) { return *(const bf16x8*)p; }
__device__ inline bf16x8 ld8(const float* p) {
    f32x4 a = *(const f32x4*)p;
    f32x4 b = *(const f32x4*)(p + 4);
    bf16x8 r;
    r[0] = (bf16)a[0]; r[1] = (bf16)a[1]; r[2] = (bf16)a[2]; r[3] = (bf16)a[3];
    r[4] = (bf16)b[0]; r[5] = (bf16)b[1]; r[6] = (bf16)b[2]; r[7] = (bf16)b[3];
    return r;
}

// async global->LDS, 16 B per lane (global_load_lds_dwordx4)
__device__ inline void async16(const bf16* g, bf16* l) {
    __builtin_amdgcn_global_load_lds(
        (const __attribute__((address_space(1))) unsigned int*)g,
        (__attribute__((address_space(3))) unsigned int*)l,
        16, 0, 0);
}

// ---- f32 -> bf16 conversion kernels ----------------------------------------
__global__ __launch_bounds__(256) void cvt1(const float* __restrict__ s,
                                            bf16* __restrict__ d, long n) {
    const long i = ((long)blockIdx.x * 256 + threadIdx.x) * 8;
    if (i < n) *(bf16x8*)(d + i) = ld8(s + i);
}
// merged x + Wq + Wk + Wv conversion (flat index; WSZ = 2^20)
__global__ __launch_bounds__(256) void cvt4(
    const float* __restrict__ x,  const float* __restrict__ Wq,
    const float* __restrict__ Wk, const float* __restrict__ Wv,
    bf16* __restrict__ xb, bf16* __restrict__ wqb,
    bf16* __restrict__ wkb, bf16* __restrict__ wvb) {
    const long i = ((long)blockIdx.x * 256 + threadIdx.x) * 8;
    const float* s; bf16* d; long off;
    if (i < SZ) { s = x; d = xb; off = i; }
    else {
        const long j = i - SZ;
        const int w = (int)(j >> 20);
        off = j & (WSZ - 1);
        s = (w == 0) ? Wq : (w == 1) ? Wk : Wv;
        d = (w == 0) ? wqb : (w == 1) ? wkb : wvb;
    }
    *(bf16x8*)(d + off) = ld8(s + off);
}
// merged x + all four weights (used when workspace has room for Wob)
__global__ __launch_bounds__(256) void cvt5(
    const float* __restrict__ x,  const float* __restrict__ Wq,
    const float* __restrict__ Wk, const float* __restrict__ Wv,
    const float* __restrict__ Wo,
    bf16* __restrict__ xb, bf16* __restrict__ wqb,
    bf16* __restrict__ wkb, bf16* __restrict__ wvb,
    bf16* __restrict__ wob) {
    const long i = ((long)blockIdx.x * 256 + threadIdx.x) * 8;
    const float* s; bf16* d; long off;
    if (i < SZ) { s = x; d = xb; off = i; }
    else {
        const long j = i - SZ;
        const int w = (int)(j >> 20);
        off = j & (WSZ - 1);
        s = (w == 0) ? Wq : (w == 1) ? Wk : (w == 2) ? Wv : Wo;
        d = (w == 0) ? wqb : (w == 1) ? wkb : (w == 2) ? wvb : wob;
    }
    *(bf16x8*)(d + off) = ld8(s + off);
}

// ---------------------------------------------------------------------------
// GEMM (all-bf16, double-buffered async staging): C = A @ W^T + bias
// 128x128 tile, BK=32, one barrier per K-step (round-7 win).
// ---------------------------------------------------------------------------
template <typename CT>
__global__ __launch_bounds__(256) void gemm_bb(
    const bf16* __restrict__ A,
    const bf16* __restrict__ W0, const bf16* __restrict__ W1, const bf16* __restrict__ W2,
    const float* __restrict__ b0, const float* __restrict__ b1, const float* __restrict__ b2,
    CT* __restrict__ C0, CT* __restrict__ C1, CT* __restrict__ C2,
    int M, int N, int K)
{
    const int z = blockIdx.z;
    const bf16* W     = (z == 0) ? W0 : ((z == 1) ? W1 : W2);
    const float* bias = (z == 0) ? b0 : ((z == 1) ? b1 : b2);
    CT* C             = (z == 0) ? C0 : ((z == 1) ? C1 : C2);

    __shared__ __align__(16) bf16 As[2][128][32];
    __shared__ __align__(16) bf16 Bs[2][128][32];

    const int tid  = threadIdx.x;
    const int lane = tid & 63;
    const int wave = tid >> 6;
    const int l15  = lane & 15;
    const int quad = lane >> 4;

    const int m0 = blockIdx.x * 128;
    const int n0 = blockIdx.y * 128;
    const int wm = (wave >> 1) * 64;
    const int wn = (wave & 1) * 64;

    f32x4 acc[4][4];
#pragma unroll
    for (int i = 0; i < 4; i++)
#pragma unroll
        for (int j = 0; j < 4; j++) acc[i][j] = f32x4{0.f, 0.f, 0.f, 0.f};

    const int r1 = tid >> 2,         c1 = (tid & 3) * 8;
    const int r2 = (tid + 256) >> 2, c2 = ((tid + 256) & 3) * 8;

    // prologue: stage K-tile 0 into buffer 0
    async16(A + (long)(m0 + r1) * K + c1, &As[0][r1][c1]);
    async16(A + (long)(m0 + r2) * K + c2, &As[0][r2][c2]);
    async16(W + (long)(n0 + r1) * K + c1, &Bs[0][r1][c1]);
    async16(W + (long)(n0 + r2) * K + c2, &Bs[0][r2][c2]);
    __syncthreads();

    const int NT = K >> 5;
    for (int t = 0; t < NT; t++) {
        const int cur = t & 1;
        if (t + 1 < NT) {
            const int k0 = (t + 1) * 32;
            async16(A + (long)(m0 + r1) * K + k0 + c1, &As[cur ^ 1][r1][c1]);
            async16(A + (long)(m0 + r2) * K + k0 + c2, &As[cur ^ 1][r2][c2]);
            async16(W + (long)(n0 + r1) * K + k0 + c1, &Bs[cur ^ 1][r1][c1]);
            async16(W + (long)(n0 + r2) * K + k0 + c2, &Bs[cur ^ 1][r2][c2]);
        }

        bf16x8 af[4], bfr[4];
#pragma unroll
        for (int t4 = 0; t4 < 4; t4++) {
            af[t4]  = *(const bf16x8*)&As[cur][wm + t4 * 16 + l15][quad * 8];
            bfr[t4] = *(const bf16x8*)&Bs[cur][wn + t4 * 16 + l15][quad * 8];
        }
#pragma unroll
        for (int i = 0; i < 4; i++)
#pragma unroll
            for (int j = 0; j < 4; j++)
                acc[i][j] = MFMA16(af[i], bfr[j], acc[i][j]);

        __syncthreads();   // drains t+1 staging (overlapped by reads+MFMA above)
    }

#pragma unroll
    for (int j = 0; j < 4; j++) {
        const float bv = bias[n0 + wn + j * 16 + l15];
        const long col = n0 + wn + j * 16 + l15;
#pragma unroll
        for (int i = 0; i < 4; i++) {
            const long row = m0 + wm + i * 16 + quad * 4;
#pragma unroll
            for (int r = 0; r < 4; r++)
                C[(row + r) * N + col] = (CT)(acc[i][j][r] + bv);
        }
    }
}

// ---------------------------------------------------------------------------
// GEMM (mixed-dtype manual staging) — kept for the zero-ws fallback path.
// ---------------------------------------------------------------------------
template <typename AT, typename CT>
__global__ __launch_bounds__(256) void gemm_bt(
    const AT* __restrict__ A,
    const float* __restrict__ W0, const float* __restrict__ W1, const float* __restrict__ W2,
    const float* __restrict__ b0, const float* __restrict__ b1, const float* __restrict__ b2,
    CT* __restrict__ C0, CT* __restrict__ C1, CT* __restrict__ C2,
    int M, int N, int K)
{
    const int z = blockIdx.z;
    const float* W    = (z == 0) ? W0 : ((z == 1) ? W1 : W2);
    const float* bias = (z == 0) ? b0 : ((z == 1) ? b1 : b2);
    CT* C             = (z == 0) ? C0 : ((z == 1) ? C1 : C2);

    __shared__ __align__(16) bf16 As[128][32];
    __shared__ __align__(16) bf16 Bs[128][32];

    const int tid  = threadIdx.x;
    const int lane = tid & 63;
    const int wave = tid >> 6;
    const int l15  = lane & 15;
    const int quad = lane >> 4;

    const int m0 = blockIdx.x * 128;
    const int n0 = blockIdx.y * 128;
    const int wm = (wave >> 1) * 64;
    const int wn = (wave & 1) * 64;

    f32x4 acc[4][4];
#pragma unroll
    for (int i = 0; i < 4; i++)
#pragma unroll
        for (int j = 0; j < 4; j++) acc[i][j] = f32x4{0.f, 0.f, 0.f, 0.f};

    const int r1 = tid >> 2,         c1 = (tid & 3) * 8;
    const int r2 = (tid + 256) >> 2, c2 = ((tid + 256) & 3) * 8;

    for (int k0 = 0; k0 < K; k0 += 32) {
        __syncthreads();
        *(bf16x8*)&As[r1][c1] = ld8(A + (long)(m0 + r1) * K + k0 + c1);
        *(bf16x8*)&As[r2][c2] = ld8(A + (long)(m0 + r2) * K + k0 + c2);
        *(bf16x8*)&Bs[r1][c1] = ld8(W + (long)(n0 + r1) * K + k0 + c1);
        *(bf16x8*)&Bs[r2][c2] = ld8(W + (long)(n0 + r2) * K + k0 + c2);
        __syncthreads();

        bf16x8 af[4], bfr[4];
#pragma unroll
        for (int t = 0; t < 4; t++) {
            af[t]  = *(const bf16x8*)&As[wm + t * 16 + l15][quad * 8];
            bfr[t] = *(const bf16x8*)&Bs[wn + t * 16 + l15][quad * 8];
        }
#pragma unroll
        for (int i = 0; i < 4; i++)
#pragma unroll
            for (int j = 0; j < 4; j++)
                acc[i][j] = MFMA16(af[i], bfr[j], acc[i][j]);
    }

#pragma unroll
    for (int j = 0; j < 4; j++) {
        const float bv = bias[n0 + wn + j * 16 + l15];
        const long col = n0 + wn + j * 16 + l15;
#pragma unroll
        for (int i = 0; i < 4; i++) {
            const long row = m0 + wm + i * 16 + quad * 4;
#pragma unroll
            for (int r = 0; r < 4; r++)
                C[(row + r) * N + col] = (CT)(acc[i][j][r] + bv);
        }
    }
}

// ---------------------------------------------------------------------------
// Flash attention v16 = v12 sync structure + FUSED softmax: per nt, the QK
// score vector is bias+mask+exp2'd and packed to bf16x4 IMMEDIATELY after
// its 2 MFMAs — sB[4]/sA[4] (32 f32 VGPRs, live across 2 phases) are gone,
// replaced by paB/paA (16 VGPRs packed). Peak pressure −16 regs (spill
// relief), and the exp2/fmaf chains interleave with the independent next-nt
// MFMAs (VALU hides under matrix pipe, m114). SM slots reduce to Pl writes.
// ---------------------------------------------------------------------------
__global__ __launch_bounds__(256, 4) void attn(
    const bf16* __restrict__ Kw, const bf16* __restrict__ Vw,
    bf16* __restrict__ QOw)
{
    const int z  = blockIdx.y;          // pair index (heavy pairs first)
    const int bh = blockIdx.x;
    const int b = bh >> 4, h = bh & 15;
    const int qtA = z, qtB = 31 - z;
    const int tid = threadIdx.x, wave = tid >> 6, lane = tid & 63;
    const int l15 = lane & 15, quad = lane >> 4;

    __shared__ __align__(16) bf16 Vt[64][72];      //  9.2 KB (single)
    __shared__ __align__(16) bf16 Kt[2][64][64];   // 16.0 KB (swizzled, dbuf)
    __shared__ __align__(16) bf16 Pl[4][16][72];   //  9.2 KB (single)

    const long base = (long)b * SEQ * DIM + h * HD;
    const int q0A = qtA * 64 + wave * 16;
    const int q0B = qtB * 64 + wave * 16;

    bf16x8 qA0, qA1, qB0, qB1;
    {
        const bf16* pA = QOw + base + (long)(q0A + l15) * DIM + quad * 8;
        qA0 = *(const bf16x8*)pA; qA1 = *(const bf16x8*)(pA + 32);
        const bf16* pB = QOw + base + (long)(q0B + l15) * DIM + quad * 8;
        qB0 = *(const bf16x8*)pB; qB1 = *(const bf16x8*)(pB + 32);
    }

    constexpr float LOG2E = 1.4426950408889634f;
    const float slope = exp2f(-0.5f * (float)(h + 1));
    const float c1 = 0.125f * LOG2E;
    const float ns = slope * LOG2E;
    const float MC = 16.0f * LOG2E;

    float lrA = 0.f, lrB = 0.f;
    f32x4 oA[4], oB[4];
#pragma unroll
    for (int d = 0; d < 4; d++) { oA[d] = f32x4{0,0,0,0}; oB[d] = f32x4{0,0,0,0}; }

    // V staging slots (fixed per thread); writes transposed+XOR into Vt
    const int sk0 = tid >> 3,         sd0 = (tid & 7) * 8;
    const int sk1 = (tid + 256) >> 3, sd1 = ((tid + 256) & 7) * 8;
    const int vc0 = sk0 ^ sd0,        vc1 = sk1 ^ sd1;

    // K-tile async staging: LDS dest linear (slot s -> 16B), global source
    // pre-swizzled so Kt[r][u*8+e] = K[r][(u^(r&7))*8+e].
    auto stageK = [&](int kt, int bi) {
#pragma unroll
        for (int t = 0; t < 2; t++) {
            const int s = tid + 256 * t;
            const int r = s >> 3, u = s & 7;
            const int gc = (u ^ (r & 7)) * 8;
            async16(Kw + base + (long)(kt * 64 + r) * DIM + gc, &Kt[bi][r][u * 8]);
        }
    };

    // prologue
    stageK(0, 0);
    {
        bf16x8 v0 = *(const bf16x8*)(Vw + base + (long)sk0 * DIM + sd0);
        bf16x8 v1 = *(const bf16x8*)(Vw + base + (long)sk1 * DIM + sd1);
#pragma unroll
        for (int i = 0; i < 8; i++) Vt[sd0 + i][vc0] = v0[i];
#pragma unroll
        for (int i = 0; i < 8; i++) Vt[sd1 + i][vc1] = v1[i];
    }
    __syncthreads();   // vmcnt(0) drain -> Kt[0] complete; Vt(0) written

    const int klq = quad * 4;
    const int qlB = wave * 16 + l15;
    const int kc0 = (quad ^ (l15 & 7)) * 8;   // swizzled K read col

    for (int kt = 0; kt <= qtB; kt++) {
        const int bi = kt & 1;
        const bool more = (kt < qtB);
        const bool dual = (kt <= qtA);   // dual => more (qtA < qtB always)

        if (more) stageK(kt + 1, bi ^ 1);   // zero-VGPR async issue at top

        // softmax bias bases (scalar, computed once per iter)
        const float t0B = fmaf(ns, (float)(kt * 64 + klq - q0B - l15), -MC);
        const float t0A = fmaf(ns, (float)(kt * 64 + klq - q0A - l15), -MC);
        const bool diagB = (kt == qtB);
        const bool diagA = (kt == qtA);

        // ---- QK^T + fused softmax: scores die immediately, packed bf16 out
        bf16x4 paB[4], paA[4];
#pragma unroll
        for (int nt = 0; nt < 4; nt++) {
            const int row = nt * 16 + l15;
            bf16x8 k0 = *(const bf16x8*)&Kt[bi][row][kc0];
            bf16x8 k1 = *(const bf16x8*)&Kt[bi][row][kc0 ^ 32];
            f32x4 a = f32x4{0,0,0,0};
            a = MFMA16(k0, qB0, a); a = MFMA16(k1, qB1, a);
            {
                const float bn = fmaf(ns, (float)(16 * nt), t0B);
                bf16x4 p4;
#pragma unroll
                for (int r = 0; r < 4; r++) {
                    float arg = fmaf(a[r], c1, fmaf(ns, (float)r, bn));
                    if (diagB && (nt * 16 + klq + r > qlB)) arg = -1e30f;
                    const float p = exp2f(arg);
                    lrB += p;
                    p4[r] = (bf16)p;
                }
                paB[nt] = p4;
            }
            if (dual) {
                f32x4 c = f32x4{0,0,0,0};
                c = MFMA16(k0, qA0, c); c = MFMA16(k1, qA1, c);
                const float bn = fmaf(ns, (float)(16 * nt), t0A);
                bf16x4 p4;
#pragma unroll
                for (int r = 0; r < 4; r++) {
                    float arg = fmaf(c[r], c1, fmaf(ns, (float)r, bn));
                    if (diagA && (nt * 16 + klq + r > qlB)) arg = -1e30f;
                    const float p = exp2f(arg);
                    lrA += p;
                    p4[r] = (bf16)p;
                }
                paA[nt] = p4;
            }
        }

        // ---- V loads for next tile (live only across PV phases)
        bf16x8 vn0, vn1;
        if (more) {
            vn0 = *(const bf16x8*)(Vw + base + (long)((kt + 1) * 64 + sk0) * DIM + sd0);
            vn1 = *(const bf16x8*)(Vw + base + (long)((kt + 1) * 64 + sk1) * DIM + sd1);
        }

        // ---- PV B: Pl write (packed) -> read -> MFMA ----
        {
#pragma unroll
            for (int nt = 0; nt < 4; nt++)
                *(bf16x4*)&Pl[wave][l15][nt * 16 + klq] = paB[nt];
            bf16x8 p0 = *(const bf16x8*)&Pl[wave][l15][quad * 8];
            bf16x8 p1 = *(const bf16x8*)&Pl[wave][l15][32 + quad * 8];
#pragma unroll
            for (int dt = 0; dt < 4; dt++) {
                const int d = dt * 16 + l15;
                const int c0 = (quad * 8) ^ (d & 56);
                bf16x8 v0 = *(const bf16x8*)&Vt[d][c0];
                bf16x8 v1 = *(const bf16x8*)&Vt[d][c0 ^ 32];
                oB[dt] = MFMA16(p0, v0, oB[dt]);
                oB[dt] = MFMA16(p1, v1, oB[dt]);
            }
        }

        // ---- PV A (wave-private Pl reuse; lgkm orders write->read) ----
        if (dual) {
#pragma unroll
            for (int nt = 0; nt < 4; nt++)
                *(bf16x4*)&Pl[wave][l15][nt * 16 + klq] = paA[nt];
            bf16x8 p0 = *(const bf16x8*)&Pl[wave][l15][quad * 8];
            bf16x8 p1 = *(const bf16x8*)&Pl[wave][l15][32 + quad * 8];
#pragma unroll
            for (int dt = 0; dt < 4; dt++) {
                const int d = dt * 16 + l15;
                const int c0 = (quad * 8) ^ (d & 56);
                bf16x8 v0 = *(const bf16x8*)&Vt[d][c0];
                bf16x8 v1 = *(const bf16x8*)&Vt[d][c0 ^ 32];
                oA[dt] = MFMA16(p0, v0, oA[dt]);
                oA[dt] = MFMA16(p1, v1, oA[dt]);
            }
        }

        __syncthreads();   // all waves done reading Vt(kt); Kt staging drained
        if (more) {
#pragma unroll
            for (int i = 0; i < 8; i++) Vt[sd0 + i][vc0] = vn0[i];
#pragma unroll
            for (int i = 0; i < 8; i++) Vt[sd1 + i][vc1] = vn1[i];
            __syncthreads();   // Vt(kt+1) visible before next PV
        }
    }

    lrB += __shfl_xor(lrB, 16, 64); lrB += __shfl_xor(lrB, 32, 64);
    lrA += __shfl_xor(lrA, 16, 64); lrA += __shfl_xor(lrA, 32, 64);
#pragma unroll
    for (int r = 0; r < 4; r++) {
        const float ivB = 1.0f / __shfl(lrB, quad * 4 + r, 64);
        const float ivA = 1.0f / __shfl(lrA, quad * 4 + r, 64);
        const long rwB = q0B + quad * 4 + r;
        const long rwA = q0A + quad * 4 + r;
#pragma unroll
        for (int dt = 0; dt < 4; dt++) {
            QOw[base + rwB * DIM + dt * 16 + l15] = (bf16)(oB[dt][r] * ivB);
            QOw[base + rwA * DIM + dt * 16 + l15] = (bf16)(oA[dt][r] * ivA);
        }
    }
}

// ---------------------------------------------------------------------------
// Fast path layout:
//   d_out lower 16.78M = xb (bf16 x); d_out +SZ = Wqb,Wkb,Wvb (2 MB each)
//   cvt5 (merged, if ws fits Wob): x + all 4 weights in one launch,
//     Wob lives at ws+SZ  ->  no serial cvt between attn and gemm3
//   gemm1 (all-bf16 async): Q->ws, K,V->x-storage
//   attn: K/V from x-storage, Q/O in ws (heavy pairs dispatched first)
//   gemm3 (all-bf16 async, f32 out): O(ws) x Wob -> d_out
// Fallback (small ws): batch-sliced path.
// ---------------------------------------------------------------------------
extern "C" void kernel_launch(void* const* d_in, const int* in_sizes, int n_in,
                              void* d_out, int out_size, void* d_ws, size_t ws_size,
                              hipStream_t stream)
{
    const float* x  = (const float*)d_in[0];
    const float* Wq = (const float*)d_in[1];
    const float* bq = (const float*)d_in[2];
    const float* Wk = (const float*)d_in[3];
    const float* bk = (const float*)d_in[4];
    const float* Wv = (const float*)d_in[5];
    const float* bv = (const float*)d_in[6];
    const float* Wo = (const float*)d_in[7];
    const float* bo = (const float*)d_in[8];
    float* out = (float*)d_out;

    dim3 blk(256, 1, 1);

    if (ws_size >= (size_t)SZ * sizeof(bf16)) {
        // ---- full-batch fast path ----
        bf16* xb  = (bf16*)d_out;            // bf16 x
        bf16* Wqb = xb + SZ;                 // bf16 weights (2 MB each)
        bf16* Wkb = Wqb + WSZ;
        bf16* Wvb = Wkb + WSZ;
        bf16* Qb  = (bf16*)d_ws;             // Q, then O in place
        bf16* Kb  = (bf16*)d_in[0];          // K in dead x-storage
        bf16* Vb  = Kb + SZ;                 // V in dead x-storage

        const bool woWs = ws_size >= (size_t)(SZ + WSZ) * sizeof(bf16);
        bf16* Wob = woWs ? (Qb + SZ) : Kb;   // ws slot, else dead-K region

        if (woWs) {
            // (SZ + 4*WSZ) / 2048 = 6144 blocks exactly
            cvt5<<<dim3(6144, 1, 1), blk, 0, stream>>>(x, Wq, Wk, Wv, Wo,
                                                       xb, Wqb, Wkb, Wvb, Wob);
        } else {
            cvt4<<<dim3(5632, 1, 1), blk, 0, stream>>>(x, Wq, Wk, Wv,
                                                       xb, Wqb, Wkb, Wvb);
        }

        dim3 g1(64, 8, 3);
        gemm_bb<bf16><<<g1, blk, 0, stream>>>(xb, Wqb, Wkb, Wvb, bq, bk, bv,
                                              Qb, Kb, Vb, BSZ * SEQ, DIM, DIM);
        dim3 g2(BSZ * NH, 16, 1);            // bh fast, pair index slow (heavy first)
        attn<<<g2, blk, 0, stream>>>(Kb, Vb, Qb);

        if (!woWs)
            cvt1<<<dim3(512, 1, 1), blk, 0, stream>>>(Wo, Wob, WSZ);

        dim3 g3(64, 8, 1);
        gemm_bb<float><<<g3, blk, 0, stream>>>(Qb, Wob, Wob, Wob, bo, bo, bo,
                                               out, out, out, BSZ * SEQ, DIM, DIM);
    } else {
        // ---- zero-workspace batch-sliced fallback ----
        bf16* outB = (bf16*)d_out;
        float* xm = const_cast<float*>(x);
        bf16* x0a = (bf16*)xm;
        bf16* x0b = x0a + BSLOT;
        bf16* x1a = (bf16*)(xm + BSLOT);

        bf16* Qs[4] = { outB + 2 * BSLOT, x0a, x0a, x0a };
        bf16* Ks[4] = { outB + 3 * BSLOT, x0b, x0b, x0b };
        bf16* Vs[4] = { outB + 4 * BSLOT, outB + 6 * BSLOT, x1a, x1a };

        dim3 gqkv(SEQ / 128, DIM / 128, 3);
        dim3 gattn(NH, 16, 1);
        dim3 gproj(SEQ / 128, DIM / 128, 1);

        for (int b = 0; b < 4; b++) {
            gemm_bt<float, bf16><<<gqkv, blk, 0, stream>>>(x + b * BSLOT, Wq, Wk, Wv,
                                                           bq, bk, bv,
                                                           Qs[b], Ks[b], Vs[b], SEQ, DIM, DIM);
            attn<<<gattn, blk, 0, stream>>>(Ks[b], Vs[b], Qs[b]);
            gemm_bt<bf16, float><<<gproj, blk, 0, stream>>>(Qs[b], Wo, Wo, Wo, bo, bo, bo,
                                                            out + b * BSLOT, out + b * BSLOT,
                                                            out + b * BSLOT, SEQ, DIM, DIM);
        }
    }
}

// Round 15
// 282.104 us; speedup vs baseline: 1.1207x; 1.1207x over previous
//
#include <hip/hip_runtime.h>
#include <hip/hip_bf16.h>

typedef __bf16 bf16;
typedef __attribute__((ext_vector_type(4))) __bf16 bf16x4;
typedef __attribute__((ext_vector_type(8))) __bf16 bf16x8;
typedef __attribute__((ext_vector_type(4))) float f32x4;

#define MFMA16(a,b,c) __builtin_amdgcn_mfma_f32_16x16x32_bf16((a),(b),(c),0,0,0)

constexpr int BSZ = 4, SEQ = 2048, DIM = 1024, NH = 16, HD = 64;
constexpr long SZ    = (long)BSZ * SEQ * DIM;   // 8M elements (full activation)
constexpr long BSLOT = (long)SEQ * DIM;         // 2M elements (one batch slot)
constexpr long WSZ   = (long)DIM * DIM;         // 1M elements (one weight matrix, 2^20)

// ---- staging loaders: 8 contiguous elements -> bf16x8 ----------------------
__device__ inline bf16x8 ld8(const bf16* p) { return *(const bf16x8*)p; }
__device__ inline bf16x8 ld8(const float* p) {
    f32x4 a = *(const f32x4*)p;
    f32x4 b = *(const f32x4*)(p + 4);
    bf16x8 r;
    r[0] = (bf16)a[0]; r[1] = (bf16)a[1]; r[2] = (bf16)a[2]; r[3] = (bf16)a[3];
    r[4] = (bf16)b[0]; r[5] = (bf16)b[1]; r[6] = (bf16)b[2]; r[7] = (bf16)b[3];
    return r;
}

// async global->LDS, 16 B per lane (global_load_lds_dwordx4)
__device__ inline void async16(const bf16* g, bf16* l) {
    __builtin_amdgcn_global_load_lds(
        (const __attribute__((address_space(1))) unsigned int*)g,
        (__attribute__((address_space(3))) unsigned int*)l,
        16, 0, 0);
}

// ---- f32 -> bf16 conversion kernels ----------------------------------------
__global__ __launch_bounds__(256) void cvt1(const float* __restrict__ s,
                                            bf16* __restrict__ d, long n) {
    const long i = ((long)blockIdx.x * 256 + threadIdx.x) * 8;
    if (i < n) *(bf16x8*)(d + i) = ld8(s + i);
}
// merged x + Wq + Wk + Wv conversion (flat index; WSZ = 2^20)
__global__ __launch_bounds__(256) void cvt4(
    const float* __restrict__ x,  const float* __restrict__ Wq,
    const float* __restrict__ Wk, const float* __restrict__ Wv,
    bf16* __restrict__ xb, bf16* __restrict__ wqb,
    bf16* __restrict__ wkb, bf16* __restrict__ wvb) {
    const long i = ((long)blockIdx.x * 256 + threadIdx.x) * 8;
    const float* s; bf16* d; long off;
    if (i < SZ) { s = x; d = xb; off = i; }
    else {
        const long j = i - SZ;
        const int w = (int)(j >> 20);
        off = j & (WSZ - 1);
        s = (w == 0) ? Wq : (w == 1) ? Wk : Wv;
        d = (w == 0) ? wqb : (w == 1) ? wkb : wvb;
    }
    *(bf16x8*)(d + off) = ld8(s + off);
}
// merged x + all four weights (used when workspace has room for Wob)
__global__ __launch_bounds__(256) void cvt5(
    const float* __restrict__ x,  const float* __restrict__ Wq,
    const float* __restrict__ Wk, const float* __restrict__ Wv,
    const float* __restrict__ Wo,
    bf16* __restrict__ xb, bf16* __restrict__ wqb,
    bf16* __restrict__ wkb, bf16* __restrict__ wvb,
    bf16* __restrict__ wob) {
    const long i = ((long)blockIdx.x * 256 + threadIdx.x) * 8;
    const float* s; bf16* d; long off;
    if (i < SZ) { s = x; d = xb; off = i; }
    else {
        const long j = i - SZ;
        const int w = (int)(j >> 20);
        off = j & (WSZ - 1);
        s = (w == 0) ? Wq : (w == 1) ? Wk : (w == 2) ? Wv : Wo;
        d = (w == 0) ? wqb : (w == 1) ? wkb : (w == 2) ? wvb : wob;
    }
    *(bf16x8*)(d + off) = ld8(s + off);
}

// ---------------------------------------------------------------------------
// GEMM (all-bf16, double-buffered async staging): C = A @ W^T + bias
// 128x128 tile, BK=32. LDS double-buffer — stage tile t+1 BEFORE computing
// tile t, ONE barrier per K-step (round-7 verified win).
// ---------------------------------------------------------------------------
template <typename CT>
__global__ __launch_bounds__(256) void gemm_bb(
    const bf16* __restrict__ A,
    const bf16* __restrict__ W0, const bf16* __restrict__ W1, const bf16* __restrict__ W2,
    const float* __restrict__ b0, const float* __restrict__ b1, const float* __restrict__ b2,
    CT* __restrict__ C0, CT* __restrict__ C1, CT* __restrict__ C2,
    int M, int N, int K)
{
    const int z = blockIdx.z;
    const bf16* W     = (z == 0) ? W0 : ((z == 1) ? W1 : W2);
    const float* bias = (z == 0) ? b0 : ((z == 1) ? b1 : b2);
    CT* C             = (z == 0) ? C0 : ((z == 1) ? C1 : C2);

    __shared__ __align__(16) bf16 As[2][128][32];
    __shared__ __align__(16) bf16 Bs[2][128][32];

    const int tid  = threadIdx.x;
    const int lane = tid & 63;
    const int wave = tid >> 6;
    const int l15  = lane & 15;
    const int quad = lane >> 4;

    const int m0 = blockIdx.x * 128;
    const int n0 = blockIdx.y * 128;
    const int wm = (wave >> 1) * 64;
    const int wn = (wave & 1) * 64;

    f32x4 acc[4][4];
#pragma unroll
    for (int i = 0; i < 4; i++)
#pragma unroll
        for (int j = 0; j < 4; j++) acc[i][j] = f32x4{0.f, 0.f, 0.f, 0.f};

    const int r1 = tid >> 2,         c1 = (tid & 3) * 8;
    const int r2 = (tid + 256) >> 2, c2 = ((tid + 256) & 3) * 8;

    // prologue: stage K-tile 0 into buffer 0
    async16(A + (long)(m0 + r1) * K + c1, &As[0][r1][c1]);
    async16(A + (long)(m0 + r2) * K + c2, &As[0][r2][c2]);
    async16(W + (long)(n0 + r1) * K + c1, &Bs[0][r1][c1]);
    async16(W + (long)(n0 + r2) * K + c2, &Bs[0][r2][c2]);
    __syncthreads();

    const int NT = K >> 5;
    for (int t = 0; t < NT; t++) {
        const int cur = t & 1;
        if (t + 1 < NT) {
            const int k0 = (t + 1) * 32;
            async16(A + (long)(m0 + r1) * K + k0 + c1, &As[cur ^ 1][r1][c1]);
            async16(A + (long)(m0 + r2) * K + k0 + c2, &As[cur ^ 1][r2][c2]);
            async16(W + (long)(n0 + r1) * K + k0 + c1, &Bs[cur ^ 1][r1][c1]);
            async16(W + (long)(n0 + r2) * K + k0 + c2, &Bs[cur ^ 1][r2][c2]);
        }

        bf16x8 af[4], bfr[4];
#pragma unroll
        for (int t4 = 0; t4 < 4; t4++) {
            af[t4]  = *(const bf16x8*)&As[cur][wm + t4 * 16 + l15][quad * 8];
            bfr[t4] = *(const bf16x8*)&Bs[cur][wn + t4 * 16 + l15][quad * 8];
        }
#pragma unroll
        for (int i = 0; i < 4; i++)
#pragma unroll
            for (int j = 0; j < 4; j++)
                acc[i][j] = MFMA16(af[i], bfr[j], acc[i][j]);

        __syncthreads();   // drains t+1 staging (overlapped by reads+MFMA above)
    }

#pragma unroll
    for (int j = 0; j < 4; j++) {
        const float bv = bias[n0 + wn + j * 16 + l15];
        const long col = n0 + wn + j * 16 + l15;
#pragma unroll
        for (int i = 0; i < 4; i++) {
            const long row = m0 + wm + i * 16 + quad * 4;
#pragma unroll
            for (int r = 0; r < 4; r++)
                C[(row + r) * N + col] = (CT)(acc[i][j][r] + bv);
        }
    }
}

// ---------------------------------------------------------------------------
// GEMM (mixed-dtype manual staging) — kept for the zero-ws fallback path.
// ---------------------------------------------------------------------------
template <typename AT, typename CT>
__global__ __launch_bounds__(256) void gemm_bt(
    const AT* __restrict__ A,
    const float* __restrict__ W0, const float* __restrict__ W1, const float* __restrict__ W2,
    const float* __restrict__ b0, const float* __restrict__ b1, const float* __restrict__ b2,
    CT* __restrict__ C0, CT* __restrict__ C1, CT* __restrict__ C2,
    int M, int N, int K)
{
    const int z = blockIdx.z;
    const float* W    = (z == 0) ? W0 : ((z == 1) ? W1 : W2);
    const float* bias = (z == 0) ? b0 : ((z == 1) ? b1 : b2);
    CT* C             = (z == 0) ? C0 : ((z == 1) ? C1 : C2);

    __shared__ __align__(16) bf16 As[128][32];
    __shared__ __align__(16) bf16 Bs[128][32];

    const int tid  = threadIdx.x;
    const int lane = tid & 63;
    const int wave = tid >> 6;
    const int l15  = lane & 15;
    const int quad = lane >> 4;

    const int m0 = blockIdx.x * 128;
    const int n0 = blockIdx.y * 128;
    const int wm = (wave >> 1) * 64;
    const int wn = (wave & 1) * 64;

    f32x4 acc[4][4];
#pragma unroll
    for (int i = 0; i < 4; i++)
#pragma unroll
        for (int j = 0; j < 4; j++) acc[i][j] = f32x4{0.f, 0.f, 0.f, 0.f};

    const int r1 = tid >> 2,         c1 = (tid & 3) * 8;
    const int r2 = (tid + 256) >> 2, c2 = ((tid + 256) & 3) * 8;

    for (int k0 = 0; k0 < K; k0 += 32) {
        __syncthreads();
        *(bf16x8*)&As[r1][c1] = ld8(A + (long)(m0 + r1) * K + k0 + c1);
        *(bf16x8*)&As[r2][c2] = ld8(A + (long)(m0 + r2) * K + k0 + c2);
        *(bf16x8*)&Bs[r1][c1] = ld8(W + (long)(n0 + r1) * K + k0 + c1);
        *(bf16x8*)&Bs[r2][c2] = ld8(W + (long)(n0 + r2) * K + k0 + c2);
        __syncthreads();

        bf16x8 af[4], bfr[4];
#pragma unroll
        for (int t = 0; t < 4; t++) {
            af[t]  = *(const bf16x8*)&As[wm + t * 16 + l15][quad * 8];
            bfr[t] = *(const bf16x8*)&Bs[wn + t * 16 + l15][quad * 8];
        }
#pragma unroll
        for (int i = 0; i < 4; i++)
#pragma unroll
            for (int j = 0; j < 4; j++)
                acc[i][j] = MFMA16(af[i], bfr[j], acc[i][j]);
    }

#pragma unroll
    for (int j = 0; j < 4; j++) {
        const float bv = bias[n0 + wn + j * 16 + l15];
        const long col = n0 + wn + j * 16 + l15;
#pragma unroll
        for (int i = 0; i < 4; i++) {
            const long row = m0 + wm + i * 16 + quad * 4;
#pragma unroll
            for (int r = 0; r < 4; r++)
                C[(row + r) * N + col] = (CT)(acc[i][j][r] + bv);
        }
    }
}

// ---------------------------------------------------------------------------
// Flash attention (best measured: 103.0 us attn, 279.0 us total, round 11).
// Dual q-tile (qtA=z, qtB=31-z) per block; single Vt buffer with deferred
// write (2 barriers/iter); Kt async double-buffer (XOR-swizzled source);
// single wave-private Pl; heavy-first dispatch (FETCH 125->37 MB).
// LDS 34.8 KB. Known residuals (characterized rounds 10-14, all attempts to
// remove were null/negative): ~80 MB scratch traffic at the 64-VGPR
// allocation; VALU-bound softmax (64 quarter-rate exp2/iter) at 3-4
// blocks/CU. Escaping either requires the 8-warp 32x32 restructure.
// ---------------------------------------------------------------------------
__global__ __launch_bounds__(256)
__attribute__((amdgpu_waves_per_eu(4, 4)))
void attn(
    const bf16* __restrict__ Kw, const bf16* __restrict__ Vw,
    bf16* __restrict__ QOw)
{
    const int z  = blockIdx.y;          // pair index (heavy pairs first)
    const int bh = blockIdx.x;
    const int b = bh >> 4, h = bh & 15;
    const int qtA = z, qtB = 31 - z;
    const int tid = threadIdx.x, wave = tid >> 6, lane = tid & 63;
    const int l15 = lane & 15, quad = lane >> 4;

    __shared__ __align__(16) bf16 Vt[64][72];      //  9.2 KB (single)
    __shared__ __align__(16) bf16 Kt[2][64][64];   // 16.0 KB (swizzled, dbuf)
    __shared__ __align__(16) bf16 Pl[4][16][72];   //  9.2 KB (single)

    const long base = (long)b * SEQ * DIM + h * HD;
    const int q0A = qtA * 64 + wave * 16;
    const int q0B = qtB * 64 + wave * 16;

    bf16x8 qA0, qA1, qB0, qB1;
    {
        const bf16* pA = QOw + base + (long)(q0A + l15) * DIM + quad * 8;
        qA0 = *(const bf16x8*)pA; qA1 = *(const bf16x8*)(pA + 32);
        const bf16* pB = QOw + base + (long)(q0B + l15) * DIM + quad * 8;
        qB0 = *(const bf16x8*)pB; qB1 = *(const bf16x8*)(pB + 32);
    }

    constexpr float LOG2E = 1.4426950408889634f;
    const float slope = exp2f(-0.5f * (float)(h + 1));
    const float c1 = 0.125f * LOG2E;
    const float ns = slope * LOG2E;
    const float MC = 16.0f * LOG2E;

    float lrA = 0.f, lrB = 0.f;
    f32x4 oA[4], oB[4];
#pragma unroll
    for (int d = 0; d < 4; d++) { oA[d] = f32x4{0,0,0,0}; oB[d] = f32x4{0,0,0,0}; }

    // V staging slots (fixed per thread); writes transposed+XOR into Vt
    const int sk0 = tid >> 3,         sd0 = (tid & 7) * 8;
    const int sk1 = (tid + 256) >> 3, sd1 = ((tid + 256) & 7) * 8;
    const int vc0 = sk0 ^ sd0,        vc1 = sk1 ^ sd1;

    // K-tile async staging: LDS dest linear (slot s -> 16B), global source
    // pre-swizzled so Kt[r][u*8+e] = K[r][(u^(r&7))*8+e].
    auto stageK = [&](int kt, int bi) {
#pragma unroll
        for (int t = 0; t < 2; t++) {
            const int s = tid + 256 * t;
            const int r = s >> 3, u = s & 7;
            const int gc = (u ^ (r & 7)) * 8;
            async16(Kw + base + (long)(kt * 64 + r) * DIM + gc, &Kt[bi][r][u * 8]);
        }
    };

    // prologue
    stageK(0, 0);
    {
        bf16x8 v0 = *(const bf16x8*)(Vw + base + (long)sk0 * DIM + sd0);
        bf16x8 v1 = *(const bf16x8*)(Vw + base + (long)sk1 * DIM + sd1);
#pragma unroll
        for (int i = 0; i < 8; i++) Vt[sd0 + i][vc0] = v0[i];
#pragma unroll
        for (int i = 0; i < 8; i++) Vt[sd1 + i][vc1] = v1[i];
    }
    __syncthreads();   // vmcnt(0) drain -> Kt[0] complete; Vt(0) written

    const int klq = quad * 4;
    const int qlB = wave * 16 + l15;
    const int kc0 = (quad ^ (l15 & 7)) * 8;   // swizzled K read col

    for (int kt = 0; kt <= qtB; kt++) {
        const int bi = kt & 1;
        const bool more = (kt < qtB);
        const bool dual = (kt <= qtA);   // dual => more (qtA < qtB always)

        bf16x8 vn0, vn1;
        if (more) {
            stageK(kt + 1, bi ^ 1);
            vn0 = *(const bf16x8*)(Vw + base + (long)((kt + 1) * 64 + sk0) * DIM + sd0);
            vn1 = *(const bf16x8*)(Vw + base + (long)((kt + 1) * 64 + sk1) * DIM + sd1);
        }

        // ---- QK^T from Kt[bi] ----
        f32x4 sB[4], sA[4];
#pragma unroll
        for (int nt = 0; nt < 4; nt++) {
            const int row = nt * 16 + l15;
            bf16x8 k0 = *(const bf16x8*)&Kt[bi][row][kc0];
            bf16x8 k1 = *(const bf16x8*)&Kt[bi][row][kc0 ^ 32];
            f32x4 a = f32x4{0,0,0,0};
            a = MFMA16(k0, qB0, a); a = MFMA16(k1, qB1, a);
            sB[nt] = a;
            if (dual) {
                f32x4 c = f32x4{0,0,0,0};
                c = MFMA16(k0, qA0, c); c = MFMA16(k1, qA1, c);
                sA[nt] = c;
            }
        }

        // ---- softmax B -> Pl ----
        {
            const float t0 = fmaf(ns, (float)(kt * 64 + klq - q0B - l15), -MC);
            const bool diag = (kt == qtB);
#pragma unroll
            for (int nt = 0; nt < 4; nt++) {
                const float bn = fmaf(ns, (float)(16 * nt), t0);
                bf16x4 p4;
#pragma unroll
                for (int r = 0; r < 4; r++) {
                    float arg = fmaf(sB[nt][r], c1, fmaf(ns, (float)r, bn));
                    if (diag && (nt * 16 + klq + r > qlB)) arg = -1e30f;
                    const float p = exp2f(arg);
                    lrB += p;
                    p4[r] = (bf16)p;
                }
                *(bf16x4*)&Pl[wave][l15][nt * 16 + klq] = p4;
            }
        }

        // ---- PV B (Vt holds V(kt)) ----
        {
            bf16x8 p0 = *(const bf16x8*)&Pl[wave][l15][quad * 8];
            bf16x8 p1 = *(const bf16x8*)&Pl[wave][l15][32 + quad * 8];
#pragma unroll
            for (int dt = 0; dt < 4; dt++) {
                const int d = dt * 16 + l15;
                const int c0 = (quad * 8) ^ (d & 56);
                bf16x8 v0 = *(const bf16x8*)&Vt[d][c0];
                bf16x8 v1 = *(const bf16x8*)&Vt[d][c0 ^ 32];
                oB[dt] = MFMA16(p0, v0, oB[dt]);
                oB[dt] = MFMA16(p1, v1, oB[dt]);
            }
        }

        // ---- softmax A -> Pl, PV A (wave-private Pl reuse; lgkm orders) ----
        if (dual) {
            const float t0 = fmaf(ns, (float)(kt * 64 + klq - q0A - l15), -MC);
            const bool diag = (kt == qtA);
#pragma unroll
            for (int nt = 0; nt < 4; nt++) {
                const float bn = fmaf(ns, (float)(16 * nt), t0);
                bf16x4 p4;
#pragma unroll
                for (int r = 0; r < 4; r++) {
                    float arg = fmaf(sA[nt][r], c1, fmaf(ns, (float)r, bn));
                    if (diag && (nt * 16 + klq + r > qlB)) arg = -1e30f;
                    const float p = exp2f(arg);
                    lrA += p;
                    p4[r] = (bf16)p;
                }
                *(bf16x4*)&Pl[wave][l15][nt * 16 + klq] = p4;
            }
            bf16x8 p0 = *(const bf16x8*)&Pl[wave][l15][quad * 8];
            bf16x8 p1 = *(const bf16x8*)&Pl[wave][l15][32 + quad * 8];
#pragma unroll
            for (int dt = 0; dt < 4; dt++) {
                const int d = dt * 16 + l15;
                const int c0 = (quad * 8) ^ (d & 56);
                bf16x8 v0 = *(const bf16x8*)&Vt[d][c0];
                bf16x8 v1 = *(const bf16x8*)&Vt[d][c0 ^ 32];
                oA[dt] = MFMA16(p0, v0, oA[dt]);
                oA[dt] = MFMA16(p1, v1, oA[dt]);
            }
        }

        __syncthreads();   // all waves done reading Vt(kt); Kt staging drained
        if (more) {
#pragma unroll
            for (int i = 0; i < 8; i++) Vt[sd0 + i][vc0] = vn0[i];
#pragma unroll
            for (int i = 0; i < 8; i++) Vt[sd1 + i][vc1] = vn1[i];
            __syncthreads();   // Vt(kt+1) visible before next PV
        }
    }

    lrB += __shfl_xor(lrB, 16, 64); lrB += __shfl_xor(lrB, 32, 64);
    lrA += __shfl_xor(lrA, 16, 64); lrA += __shfl_xor(lrA, 32, 64);
#pragma unroll
    for (int r = 0; r < 4; r++) {
        const float ivB = 1.0f / __shfl(lrB, quad * 4 + r, 64);
        const float ivA = 1.0f / __shfl(lrA, quad * 4 + r, 64);
        const long rwB = q0B + quad * 4 + r;
        const long rwA = q0A + quad * 4 + r;
#pragma unroll
        for (int dt = 0; dt < 4; dt++) {
            QOw[base + rwB * DIM + dt * 16 + l15] = (bf16)(oB[dt][r] * ivB);
            QOw[base + rwA * DIM + dt * 16 + l15] = (bf16)(oA[dt][r] * ivA);
        }
    }
}

// ---------------------------------------------------------------------------
// Fast path layout:
//   d_out lower 16.78M = xb (bf16 x); d_out +SZ = Wqb,Wkb,Wvb (2 MB each)
//   cvt5 (merged, if ws fits Wob): x + all 4 weights in one launch,
//     Wob lives at ws+SZ  ->  no serial cvt between attn and gemm3
//   gemm1 (all-bf16 async): Q->ws, K,V->x-storage
//   attn: K/V from x-storage, Q/O in ws (heavy pairs dispatched first)
//   gemm3 (all-bf16 async, f32 out): O(ws) x Wob -> d_out
// Fallback (small ws): batch-sliced path.
// ---------------------------------------------------------------------------
extern "C" void kernel_launch(void* const* d_in, const int* in_sizes, int n_in,
                              void* d_out, int out_size, void* d_ws, size_t ws_size,
                              hipStream_t stream)
{
    const float* x  = (const float*)d_in[0];
    const float* Wq = (const float*)d_in[1];
    const float* bq = (const float*)d_in[2];
    const float* Wk = (const float*)d_in[3];
    const float* bk = (const float*)d_in[4];
    const float* Wv = (const float*)d_in[5];
    const float* bv = (const float*)d_in[6];
    const float* Wo = (const float*)d_in[7];
    const float* bo = (const float*)d_in[8];
    float* out = (float*)d_out;

    dim3 blk(256, 1, 1);

    if (ws_size >= (size_t)SZ * sizeof(bf16)) {
        // ---- full-batch fast path ----
        bf16* xb  = (bf16*)d_out;            // bf16 x
        bf16* Wqb = xb + SZ;                 // bf16 weights (2 MB each)
        bf16* Wkb = Wqb + WSZ;
        bf16* Wvb = Wkb + WSZ;
        bf16* Qb  = (bf16*)d_ws;             // Q, then O in place
        bf16* Kb  = (bf16*)d_in[0];          // K in dead x-storage
        bf16* Vb  = Kb + SZ;                 // V in dead x-storage

        const bool woWs = ws_size >= (size_t)(SZ + WSZ) * sizeof(bf16);
        bf16* Wob = woWs ? (Qb + SZ) : Kb;   // ws slot, else dead-K region

        if (woWs) {
            // (SZ + 4*WSZ) / 2048 = 6144 blocks exactly
            cvt5<<<dim3(6144, 1, 1), blk, 0, stream>>>(x, Wq, Wk, Wv, Wo,
                                                       xb, Wqb, Wkb, Wvb, Wob);
        } else {
            cvt4<<<dim3(5632, 1, 1), blk, 0, stream>>>(x, Wq, Wk, Wv,
                                                       xb, Wqb, Wkb, Wvb);
        }

        dim3 g1(64, 8, 3);
        gemm_bb<bf16><<<g1, blk, 0, stream>>>(xb, Wqb, Wkb, Wvb, bq, bk, bv,
                                              Qb, Kb, Vb, BSZ * SEQ, DIM, DIM);
        dim3 g2(BSZ * NH, 16, 1);            // bh fast, pair index slow (heavy first)
        attn<<<g2, blk, 0, stream>>>(Kb, Vb, Qb);

        if (!woWs)
            cvt1<<<dim3(512, 1, 1), blk, 0, stream>>>(Wo, Wob, WSZ);

        dim3 g3(64, 8, 1);
        gemm_bb<float><<<g3, blk, 0, stream>>>(Qb, Wob, Wob, Wob, bo, bo, bo,
                                               out, out, out, BSZ * SEQ, DIM, DIM);
    } else {
        // ---- zero-workspace batch-sliced fallback ----
        bf16* outB = (bf16*)d_out;
        float* xm = const_cast<float*>(x);
        bf16* x0a = (bf16*)xm;
        bf16* x0b = x0a + BSLOT;
        bf16* x1a = (bf16*)(xm + BSLOT);

        bf16* Qs[4] = { outB + 2 * BSLOT, x0a, x0a, x0a };
        bf16* Ks[4] = { outB + 3 * BSLOT, x0b, x0b, x0b };
        bf16* Vs[4] = { outB + 4 * BSLOT, outB + 6 * BSLOT, x1a, x1a };

        dim3 gqkv(SEQ / 128, DIM / 128, 3);
        dim3 gattn(NH, 16, 1);
        dim3 gproj(SEQ / 128, DIM / 128, 1);

        for (int b = 0; b < 4; b++) {
            gemm_bt<float, bf16><<<gqkv, blk, 0, stream>>>(x + b * BSLOT, Wq, Wk, Wv,
                                                           bq, bk, bv,
                                                           Qs[b], Ks[b], Vs[b], SEQ, DIM, DIM);
            attn<<<gattn, blk, 0, stream>>>(Ks[b], Vs[b], Qs[b]);
            gemm_bt<bf16, float><<<gproj, blk, 0, stream>>>(Qs[b], Wo, Wo, Wo, bo, bo, bo,
                                                            out + b * BSLOT, out + b * BSLOT,
                                                            out + b * BSLOT, SEQ, DIM, DIM);
        }
    }
}

// Round 16
// 278.148 us; speedup vs baseline: 1.1367x; 1.0142x over previous
//
#include <hip/hip_runtime.h>
#include <hip/hip_bf16.h>

typedef __bf16 bf16;
typedef __attribute__((ext_vector_type(4))) __bf16 bf16x4;
typedef __attribute__((ext_vector_type(8))) __bf16 bf16x8;
typedef __attribute__((ext_vector_type(4))) float f32x4;

#define MFMA16(a,b,c) __builtin_amdgcn_mfma_f32_16x16x32_bf16((a),(b),(c),0,0,0)

constexpr int BSZ = 4, SEQ = 2048, DIM = 1024, NH = 16, HD = 64;
constexpr long SZ    = (long)BSZ * SEQ * DIM;   // 8M elements (full activation)
constexpr long BSLOT = (long)SEQ * DIM;         // 2M elements (one batch slot)
constexpr long WSZ   = (long)DIM * DIM;         // 1M elements (one weight matrix, 2^20)

// ---- staging loaders: 8 contiguous elements -> bf16x8 ----------------------
__device__ inline bf16x8 ld8(const bf16* p) { return *(const bf16x8*)p; }
__device__ inline bf16x8 ld8(const float* p) {
    f32x4 a = *(const f32x4*)p;
    f32x4 b = *(const f32x4*)(p + 4);
    bf16x8 r;
    r[0] = (bf16)a[0]; r[1] = (bf16)a[1]; r[2] = (bf16)a[2]; r[3] = (bf16)a[3];
    r[4] = (bf16)b[0]; r[5] = (bf16)b[1]; r[6] = (bf16)b[2]; r[7] = (bf16)b[3];
    return r;
}

// async global->LDS, 16 B per lane (global_load_lds_dwordx4)
__device__ inline void async16(const bf16* g, bf16* l) {
    __builtin_amdgcn_global_load_lds(
        (const __attribute__((address_space(1))) unsigned int*)g,
        (__attribute__((address_space(3))) unsigned int*)l,
        16, 0, 0);
}

// ---- f32 -> bf16 conversion kernels ----------------------------------------
__global__ __launch_bounds__(256) void cvt1(const float* __restrict__ s,
                                            bf16* __restrict__ d, long n) {
    const long i = ((long)blockIdx.x * 256 + threadIdx.x) * 8;
    if (i < n) *(bf16x8*)(d + i) = ld8(s + i);
}
// merged x + Wq + Wk + Wv conversion (flat index; WSZ = 2^20)
__global__ __launch_bounds__(256) void cvt4(
    const float* __restrict__ x,  const float* __restrict__ Wq,
    const float* __restrict__ Wk, const float* __restrict__ Wv,
    bf16* __restrict__ xb, bf16* __restrict__ wqb,
    bf16* __restrict__ wkb, bf16* __restrict__ wvb) {
    const long i = ((long)blockIdx.x * 256 + threadIdx.x) * 8;
    const float* s; bf16* d; long off;
    if (i < SZ) { s = x; d = xb; off = i; }
    else {
        const long j = i - SZ;
        const int w = (int)(j >> 20);
        off = j & (WSZ - 1);
        s = (w == 0) ? Wq : (w == 1) ? Wk : Wv;
        d = (w == 0) ? wqb : (w == 1) ? wkb : wvb;
    }
    *(bf16x8*)(d + off) = ld8(s + off);
}
// merged x + all four weights (used when workspace has room for Wob)
__global__ __launch_bounds__(256) void cvt5(
    const float* __restrict__ x,  const float* __restrict__ Wq,
    const float* __restrict__ Wk, const float* __restrict__ Wv,
    const float* __restrict__ Wo,
    bf16* __restrict__ xb, bf16* __restrict__ wqb,
    bf16* __restrict__ wkb, bf16* __restrict__ wvb,
    bf16* __restrict__ wob) {
    const long i = ((long)blockIdx.x * 256 + threadIdx.x) * 8;
    const float* s; bf16* d; long off;
    if (i < SZ) { s = x; d = xb; off = i; }
    else {
        const long j = i - SZ;
        const int w = (int)(j >> 20);
        off = j & (WSZ - 1);
        s = (w == 0) ? Wq : (w == 1) ? Wk : (w == 2) ? Wv : Wo;
        d = (w == 0) ? wqb : (w == 1) ? wkb : (w == 2) ? wvb : wob;
    }
    *(bf16x8*)(d + off) = ld8(s + off);
}

// ---------------------------------------------------------------------------
// GEMM (all-bf16, double-buffered async staging): C = A @ W^T + bias
// 128x128 tile, BK=32. LDS double-buffer — stage tile t+1 BEFORE computing
// tile t, ONE barrier per K-step (round-7 verified win).
// ---------------------------------------------------------------------------
template <typename CT>
__global__ __launch_bounds__(256) void gemm_bb(
    const bf16* __restrict__ A,
    const bf16* __restrict__ W0, const bf16* __restrict__ W1, const bf16* __restrict__ W2,
    const float* __restrict__ b0, const float* __restrict__ b1, const float* __restrict__ b2,
    CT* __restrict__ C0, CT* __restrict__ C1, CT* __restrict__ C2,
    int M, int N, int K)
{
    const int z = blockIdx.z;
    const bf16* W     = (z == 0) ? W0 : ((z == 1) ? W1 : W2);
    const float* bias = (z == 0) ? b0 : ((z == 1) ? b1 : b2);
    CT* C             = (z == 0) ? C0 : ((z == 1) ? C1 : C2);

    __shared__ __align__(16) bf16 As[2][128][32];
    __shared__ __align__(16) bf16 Bs[2][128][32];

    const int tid  = threadIdx.x;
    const int lane = tid & 63;
    const int wave = tid >> 6;
    const int l15  = lane & 15;
    const int quad = lane >> 4;

    const int m0 = blockIdx.x * 128;
    const int n0 = blockIdx.y * 128;
    const int wm = (wave >> 1) * 64;
    const int wn = (wave & 1) * 64;

    f32x4 acc[4][4];
#pragma unroll
    for (int i = 0; i < 4; i++)
#pragma unroll
        for (int j = 0; j < 4; j++) acc[i][j] = f32x4{0.f, 0.f, 0.f, 0.f};

    const int r1 = tid >> 2,         c1 = (tid & 3) * 8;
    const int r2 = (tid + 256) >> 2, c2 = ((tid + 256) & 3) * 8;

    // prologue: stage K-tile 0 into buffer 0
    async16(A + (long)(m0 + r1) * K + c1, &As[0][r1][c1]);
    async16(A + (long)(m0 + r2) * K + c2, &As[0][r2][c2]);
    async16(W + (long)(n0 + r1) * K + c1, &Bs[0][r1][c1]);
    async16(W + (long)(n0 + r2) * K + c2, &Bs[0][r2][c2]);
    __syncthreads();

    const int NT = K >> 5;
    for (int t = 0; t < NT; t++) {
        const int cur = t & 1;
        if (t + 1 < NT) {
            const int k0 = (t + 1) * 32;
            async16(A + (long)(m0 + r1) * K + k0 + c1, &As[cur ^ 1][r1][c1]);
            async16(A + (long)(m0 + r2) * K + k0 + c2, &As[cur ^ 1][r2][c2]);
            async16(W + (long)(n0 + r1) * K + k0 + c1, &Bs[cur ^ 1][r1][c1]);
            async16(W + (long)(n0 + r2) * K + k0 + c2, &Bs[cur ^ 1][r2][c2]);
        }

        bf16x8 af[4], bfr[4];
#pragma unroll
        for (int t4 = 0; t4 < 4; t4++) {
            af[t4]  = *(const bf16x8*)&As[cur][wm + t4 * 16 + l15][quad * 8];
            bfr[t4] = *(const bf16x8*)&Bs[cur][wn + t4 * 16 + l15][quad * 8];
        }
#pragma unroll
        for (int i = 0; i < 4; i++)
#pragma unroll
            for (int j = 0; j < 4; j++)
                acc[i][j] = MFMA16(af[i], bfr[j], acc[i][j]);

        __syncthreads();   // drains t+1 staging (overlapped by reads+MFMA above)
    }

#pragma unroll
    for (int j = 0; j < 4; j++) {
        const float bv = bias[n0 + wn + j * 16 + l15];
        const long col = n0 + wn + j * 16 + l15;
#pragma unroll
        for (int i = 0; i < 4; i++) {
            const long row = m0 + wm + i * 16 + quad * 4;
#pragma unroll
            for (int r = 0; r < 4; r++)
                C[(row + r) * N + col] = (CT)(acc[i][j][r] + bv);
        }
    }
}

// ---------------------------------------------------------------------------
// GEMM (mixed-dtype manual staging) — kept for the zero-ws fallback path.
// ---------------------------------------------------------------------------
template <typename AT, typename CT>
__global__ __launch_bounds__(256) void gemm_bt(
    const AT* __restrict__ A,
    const float* __restrict__ W0, const float* __restrict__ W1, const float* __restrict__ W2,
    const float* __restrict__ b0, const float* __restrict__ b1, const float* __restrict__ b2,
    CT* __restrict__ C0, CT* __restrict__ C1, CT* __restrict__ C2,
    int M, int N, int K)
{
    const int z = blockIdx.z;
    const float* W    = (z == 0) ? W0 : ((z == 1) ? W1 : W2);
    const float* bias = (z == 0) ? b0 : ((z == 1) ? b1 : b2);
    CT* C             = (z == 0) ? C0 : ((z == 1) ? C1 : C2);

    __shared__ __align__(16) bf16 As[128][32];
    __shared__ __align__(16) bf16 Bs[128][32];

    const int tid  = threadIdx.x;
    const int lane = tid & 63;
    const int wave = tid >> 6;
    const int l15  = lane & 15;
    const int quad = lane >> 4;

    const int m0 = blockIdx.x * 128;
    const int n0 = blockIdx.y * 128;
    const int wm = (wave >> 1) * 64;
    const int wn = (wave & 1) * 64;

    f32x4 acc[4][4];
#pragma unroll
    for (int i = 0; i < 4; i++)
#pragma unroll
        for (int j = 0; j < 4; j++) acc[i][j] = f32x4{0.f, 0.f, 0.f, 0.f};

    const int r1 = tid >> 2,         c1 = (tid & 3) * 8;
    const int r2 = (tid + 256) >> 2, c2 = ((tid + 256) & 3) * 8;

    for (int k0 = 0; k0 < K; k0 += 32) {
        __syncthreads();
        *(bf16x8*)&As[r1][c1] = ld8(A + (long)(m0 + r1) * K + k0 + c1);
        *(bf16x8*)&As[r2][c2] = ld8(A + (long)(m0 + r2) * K + k0 + c2);
        *(bf16x8*)&Bs[r1][c1] = ld8(W + (long)(n0 + r1) * K + k0 + c1);
        *(bf16x8*)&Bs[r2][c2] = ld8(W + (long)(n0 + r2) * K + k0 + c2);
        __syncthreads();

        bf16x8 af[4], bfr[4];
#pragma unroll
        for (int t = 0; t < 4; t++) {
            af[t]  = *(const bf16x8*)&As[wm + t * 16 + l15][quad * 8];
            bfr[t] = *(const bf16x8*)&Bs[wn + t * 16 + l15][quad * 8];
        }
#pragma unroll
        for (int i = 0; i < 4; i++)
#pragma unroll
            for (int j = 0; j < 4; j++)
                acc[i][j] = MFMA16(af[i], bfr[j], acc[i][j]);
    }

#pragma unroll
    for (int j = 0; j < 4; j++) {
        const float bv = bias[n0 + wn + j * 16 + l15];
        const long col = n0 + wn + j * 16 + l15;
#pragma unroll
        for (int i = 0; i < 4; i++) {
            const long row = m0 + wm + i * 16 + quad * 4;
#pragma unroll
            for (int r = 0; r < 4; r++)
                C[(row + r) * N + col] = (CT)(acc[i][j][r] + bv);
        }
    }
}

// ---------------------------------------------------------------------------
// Flash attention v17 = round-15 best body + s_setprio(1) around the QK and
// PV MFMA clusters ONLY (T5 isolated — round 8 bundled it with the MFMA
// row-sum, which confounded the A/B; m191 measured +4-7% for setprio alone
// on independent-block attn, which this is). No other change.
// ---------------------------------------------------------------------------
__global__ __launch_bounds__(256, 4) void attn(
    const bf16* __restrict__ Kw, const bf16* __restrict__ Vw,
    bf16* __restrict__ QOw)
{
    const int z  = blockIdx.y;          // pair index (heavy pairs first)
    const int bh = blockIdx.x;
    const int b = bh >> 4, h = bh & 15;
    const int qtA = z, qtB = 31 - z;
    const int tid = threadIdx.x, wave = tid >> 6, lane = tid & 63;
    const int l15 = lane & 15, quad = lane >> 4;

    __shared__ __align__(16) bf16 Vt[64][72];      //  9.2 KB (single)
    __shared__ __align__(16) bf16 Kt[2][64][64];   // 16.0 KB (swizzled, dbuf)
    __shared__ __align__(16) bf16 Pl[4][16][72];   //  9.2 KB (single)

    const long base = (long)b * SEQ * DIM + h * HD;
    const int q0A = qtA * 64 + wave * 16;
    const int q0B = qtB * 64 + wave * 16;

    bf16x8 qA0, qA1, qB0, qB1;
    {
        const bf16* pA = QOw + base + (long)(q0A + l15) * DIM + quad * 8;
        qA0 = *(const bf16x8*)pA; qA1 = *(const bf16x8*)(pA + 32);
        const bf16* pB = QOw + base + (long)(q0B + l15) * DIM + quad * 8;
        qB0 = *(const bf16x8*)pB; qB1 = *(const bf16x8*)(pB + 32);
    }

    constexpr float LOG2E = 1.4426950408889634f;
    const float slope = exp2f(-0.5f * (float)(h + 1));
    const float c1 = 0.125f * LOG2E;
    const float ns = slope * LOG2E;
    const float MC = 16.0f * LOG2E;

    float lrA = 0.f, lrB = 0.f;
    f32x4 oA[4], oB[4];
#pragma unroll
    for (int d = 0; d < 4; d++) { oA[d] = f32x4{0,0,0,0}; oB[d] = f32x4{0,0,0,0}; }

    // V staging slots (fixed per thread); writes transposed+XOR into Vt
    const int sk0 = tid >> 3,         sd0 = (tid & 7) * 8;
    const int sk1 = (tid + 256) >> 3, sd1 = ((tid + 256) & 7) * 8;
    const int vc0 = sk0 ^ sd0,        vc1 = sk1 ^ sd1;

    // K-tile async staging: LDS dest linear (slot s -> 16B), global source
    // pre-swizzled so Kt[r][u*8+e] = K[r][(u^(r&7))*8+e].
    auto stageK = [&](int kt, int bi) {
#pragma unroll
        for (int t = 0; t < 2; t++) {
            const int s = tid + 256 * t;
            const int r = s >> 3, u = s & 7;
            const int gc = (u ^ (r & 7)) * 8;
            async16(Kw + base + (long)(kt * 64 + r) * DIM + gc, &Kt[bi][r][u * 8]);
        }
    };

    // prologue
    stageK(0, 0);
    {
        bf16x8 v0 = *(const bf16x8*)(Vw + base + (long)sk0 * DIM + sd0);
        bf16x8 v1 = *(const bf16x8*)(Vw + base + (long)sk1 * DIM + sd1);
#pragma unroll
        for (int i = 0; i < 8; i++) Vt[sd0 + i][vc0] = v0[i];
#pragma unroll
        for (int i = 0; i < 8; i++) Vt[sd1 + i][vc1] = v1[i];
    }
    __syncthreads();   // vmcnt(0) drain -> Kt[0] complete; Vt(0) written

    const int klq = quad * 4;
    const int qlB = wave * 16 + l15;
    const int kc0 = (quad ^ (l15 & 7)) * 8;   // swizzled K read col

    for (int kt = 0; kt <= qtB; kt++) {
        const int bi = kt & 1;
        const bool more = (kt < qtB);
        const bool dual = (kt <= qtA);   // dual => more (qtA < qtB always)

        bf16x8 vn0, vn1;
        if (more) {
            stageK(kt + 1, bi ^ 1);
            vn0 = *(const bf16x8*)(Vw + base + (long)((kt + 1) * 64 + sk0) * DIM + sd0);
            vn1 = *(const bf16x8*)(Vw + base + (long)((kt + 1) * 64 + sk1) * DIM + sd1);
        }

        // ---- QK^T from Kt[bi] ----
        f32x4 sB[4], sA[4];
        __builtin_amdgcn_s_setprio(1);
#pragma unroll
        for (int nt = 0; nt < 4; nt++) {
            const int row = nt * 16 + l15;
            bf16x8 k0 = *(const bf16x8*)&Kt[bi][row][kc0];
            bf16x8 k1 = *(const bf16x8*)&Kt[bi][row][kc0 ^ 32];
            f32x4 a = f32x4{0,0,0,0};
            a = MFMA16(k0, qB0, a); a = MFMA16(k1, qB1, a);
            sB[nt] = a;
            if (dual) {
                f32x4 c = f32x4{0,0,0,0};
                c = MFMA16(k0, qA0, c); c = MFMA16(k1, qA1, c);
                sA[nt] = c;
            }
        }
        __builtin_amdgcn_s_setprio(0);

        // ---- softmax B -> Pl ----
        {
            const float t0 = fmaf(ns, (float)(kt * 64 + klq - q0B - l15), -MC);
            const bool diag = (kt == qtB);
#pragma unroll
            for (int nt = 0; nt < 4; nt++) {
                const float bn = fmaf(ns, (float)(16 * nt), t0);
                bf16x4 p4;
#pragma unroll
                for (int r = 0; r < 4; r++) {
                    float arg = fmaf(sB[nt][r], c1, fmaf(ns, (float)r, bn));
                    if (diag && (nt * 16 + klq + r > qlB)) arg = -1e30f;
                    const float p = exp2f(arg);
                    lrB += p;
                    p4[r] = (bf16)p;
                }
                *(bf16x4*)&Pl[wave][l15][nt * 16 + klq] = p4;
            }
        }

        // ---- PV B (Vt holds V(kt)) ----
        {
            bf16x8 p0 = *(const bf16x8*)&Pl[wave][l15][quad * 8];
            bf16x8 p1 = *(const bf16x8*)&Pl[wave][l15][32 + quad * 8];
            __builtin_amdgcn_s_setprio(1);
#pragma unroll
            for (int dt = 0; dt < 4; dt++) {
                const int d = dt * 16 + l15;
                const int c0 = (quad * 8) ^ (d & 56);
                bf16x8 v0 = *(const bf16x8*)&Vt[d][c0];
                bf16x8 v1 = *(const bf16x8*)&Vt[d][c0 ^ 32];
                oB[dt] = MFMA16(p0, v0, oB[dt]);
                oB[dt] = MFMA16(p1, v1, oB[dt]);
            }
            __builtin_amdgcn_s_setprio(0);
        }

        // ---- softmax A -> Pl, PV A (wave-private Pl reuse; lgkm orders) ----
        if (dual) {
            const float t0 = fmaf(ns, (float)(kt * 64 + klq - q0A - l15), -MC);
            const bool diag = (kt == qtA);
#pragma unroll
            for (int nt = 0; nt < 4; nt++) {
                const float bn = fmaf(ns, (float)(16 * nt), t0);
                bf16x4 p4;
#pragma unroll
                for (int r = 0; r < 4; r++) {
                    float arg = fmaf(sA[nt][r], c1, fmaf(ns, (float)r, bn));
                    if (diag && (nt * 16 + klq + r > qlB)) arg = -1e30f;
                    const float p = exp2f(arg);
                    lrA += p;
                    p4[r] = (bf16)p;
                }
                *(bf16x4*)&Pl[wave][l15][nt * 16 + klq] = p4;
            }
            bf16x8 p0 = *(const bf16x8*)&Pl[wave][l15][quad * 8];
            bf16x8 p1 = *(const bf16x8*)&Pl[wave][l15][32 + quad * 8];
            __builtin_amdgcn_s_setprio(1);
#pragma unroll
            for (int dt = 0; dt < 4; dt++) {
                const int d = dt * 16 + l15;
                const int c0 = (quad * 8) ^ (d & 56);
                bf16x8 v0 = *(const bf16x8*)&Vt[d][c0];
                bf16x8 v1 = *(const bf16x8*)&Vt[d][c0 ^ 32];
                oA[dt] = MFMA16(p0, v0, oA[dt]);
                oA[dt] = MFMA16(p1, v1, oA[dt]);
            }
            __builtin_amdgcn_s_setprio(0);
        }

        __syncthreads();   // all waves done reading Vt(kt); Kt staging drained
        if (more) {
#pragma unroll
            for (int i = 0; i < 8; i++) Vt[sd0 + i][vc0] = vn0[i];
#pragma unroll
            for (int i = 0; i < 8; i++) Vt[sd1 + i][vc1] = vn1[i];
            __syncthreads();   // Vt(kt+1) visible before next PV
        }
    }

    lrB += __shfl_xor(lrB, 16, 64); lrB += __shfl_xor(lrB, 32, 64);
    lrA += __shfl_xor(lrA, 16, 64); lrA += __shfl_xor(lrA, 32, 64);
#pragma unroll
    for (int r = 0; r < 4; r++) {
        const float ivB = 1.0f / __shfl(lrB, quad * 4 + r, 64);
        const float ivA = 1.0f / __shfl(lrA, quad * 4 + r, 64);
        const long rwB = q0B + quad * 4 + r;
        const long rwA = q0A + quad * 4 + r;
#pragma unroll
        for (int dt = 0; dt < 4; dt++) {
            QOw[base + rwB * DIM + dt * 16 + l15] = (bf16)(oB[dt][r] * ivB);
            QOw[base + rwA * DIM + dt * 16 + l15] = (bf16)(oA[dt][r] * ivA);
        }
    }
}

// ---------------------------------------------------------------------------
// Fast path layout:
//   d_out lower 16.78M = xb (bf16 x); d_out +SZ = Wqb,Wkb,Wvb (2 MB each)
//   cvt5 (merged, if ws fits Wob): x + all 4 weights in one launch,
//     Wob lives at ws+SZ  ->  no serial cvt between attn and gemm3
//   gemm1 (all-bf16 async): Q->ws, K,V->x-storage
//   attn: K/V from x-storage, Q/O in ws (heavy pairs dispatched first)
//   gemm3 (all-bf16 async, f32 out): O(ws) x Wob -> d_out
// Fallback (small ws): batch-sliced path.
// ---------------------------------------------------------------------------
extern "C" void kernel_launch(void* const* d_in, const int* in_sizes, int n_in,
                              void* d_out, int out_size, void* d_ws, size_t ws_size,
                              hipStream_t stream)
{
    const float* x  = (const float*)d_in[0];
    const float* Wq = (const float*)d_in[1];
    const float* bq = (const float*)d_in[2];
    const float* Wk = (const float*)d_in[3];
    const float* bk = (const float*)d_in[4];
    const float* Wv = (const float*)d_in[5];
    const float* bv = (const float*)d_in[6];
    const float* Wo = (const float*)d_in[7];
    const float* bo = (const float*)d_in[8];
    float* out = (float*)d_out;

    dim3 blk(256, 1, 1);

    if (ws_size >= (size_t)SZ * sizeof(bf16)) {
        // ---- full-batch fast path ----
        bf16* xb  = (bf16*)d_out;            // bf16 x
        bf16* Wqb = xb + SZ;                 // bf16 weights (2 MB each)
        bf16* Wkb = Wqb + WSZ;
        bf16* Wvb = Wkb + WSZ;
        bf16* Qb  = (bf16*)d_ws;             // Q, then O in place
        bf16* Kb  = (bf16*)d_in[0];          // K in dead x-storage
        bf16* Vb  = Kb + SZ;                 // V in dead x-storage

        const bool woWs = ws_size >= (size_t)(SZ + WSZ) * sizeof(bf16);
        bf16* Wob = woWs ? (Qb + SZ) : Kb;   // ws slot, else dead-K region

        if (woWs) {
            // (SZ + 4*WSZ) / 2048 = 6144 blocks exactly
            cvt5<<<dim3(6144, 1, 1), blk, 0, stream>>>(x, Wq, Wk, Wv, Wo,
                                                       xb, Wqb, Wkb, Wvb, Wob);
        } else {
            cvt4<<<dim3(5632, 1, 1), blk, 0, stream>>>(x, Wq, Wk, Wv,
                                                       xb, Wqb, Wkb, Wvb);
        }

        dim3 g1(64, 8, 3);
        gemm_bb<bf16><<<g1, blk, 0, stream>>>(xb, Wqb, Wkb, Wvb, bq, bk, bv,
                                              Qb, Kb, Vb, BSZ * SEQ, DIM, DIM);
        dim3 g2(BSZ * NH, 16, 1);            // bh fast, pair index slow (heavy first)
        attn<<<g2, blk, 0, stream>>>(Kb, Vb, Qb);

        if (!woWs)
            cvt1<<<dim3(512, 1, 1), blk, 0, stream>>>(Wo, Wob, WSZ);

        dim3 g3(64, 8, 1);
        gemm_bb<float><<<g3, blk, 0, stream>>>(Qb, Wob, Wob, Wob, bo, bo, bo,
                                               out, out, out, BSZ * SEQ, DIM, DIM);
    } else {
        // ---- zero-workspace batch-sliced fallback ----
        bf16* outB = (bf16*)d_out;
        float* xm = const_cast<float*>(x);
        bf16* x0a = (bf16*)xm;
        bf16* x0b = x0a + BSLOT;
        bf16* x1a = (bf16*)(xm + BSLOT);

        bf16* Qs[4] = { outB + 2 * BSLOT, x0a, x0a, x0a };
        bf16* Ks[4] = { outB + 3 * BSLOT, x0b, x0b, x0b };
        bf16* Vs[4] = { outB + 4 * BSLOT, outB + 6 * BSLOT, x1a, x1a };

        dim3 gqkv(SEQ / 128, DIM / 128, 3);
        dim3 gattn(NH, 16, 1);
        dim3 gproj(SEQ / 128, DIM / 128, 1);

        for (int b = 0; b < 4; b++) {
            gemm_bt<float, bf16><<<gqkv, blk, 0, stream>>>(x + b * BSLOT, Wq, Wk, Wv,
                                                           bq, bk, bv,
                                                           Qs[b], Ks[b], Vs[b], SEQ, DIM, DIM);
            attn<<<gattn, blk, 0, stream>>>(Ks[b], Vs[b], Qs[b]);
            gemm_bt<bf16, float><<<gproj, blk, 0, stream>>>(Qs[b], Wo, Wo, Wo, bo, bo, bo,
                                                            out + b * BSLOT, out + b * BSLOT,
                                                            out + b * BSLOT, SEQ, DIM, DIM);
        }
    }
}